// Round 1
// baseline (320.393 us; speedup 1.0000x reference)
//
#include <hip/hip_runtime.h>
#include <math.h>

#define E_  8
#define H_  2048
#define I_  768
#define T_  1024
#define K_  2
#define TK_ 2048
#define GU_ 1536   // 2*I

typedef short  short8 __attribute__((ext_vector_type(8)));
typedef __bf16 bf16x8 __attribute__((ext_vector_type(8)));
typedef float  f32x4  __attribute__((ext_vector_type(4)));

static __device__ __forceinline__ short f2bf(float f) {
  union { float f; unsigned u; } v; v.f = f;
  unsigned r = (v.u + 0x7fffu + ((v.u >> 16) & 1u)) >> 16;
  return (short)r;
}

// ---------------------------------------------------------------- routing ---
__global__ __launch_bounds__(256) void route_kernel(
    const int* __restrict__ sel, int* __restrict__ offs,
    int* __restrict__ rows, int* __restrict__ inv) {
  __shared__ int cnt[E_], cur[E_], loff[E_ + 1];
  int t = threadIdx.x;
  if (t < E_) { cnt[t] = 0; cur[t] = 0; }
  __syncthreads();
  for (int p = t; p < TK_; p += 256) atomicAdd(&cnt[sel[p]], 1);
  __syncthreads();
  if (t == 0) {
    int s = 0;
    for (int e = 0; e < E_; ++e) { loff[e] = s; s += cnt[e]; }
    loff[E_] = s;
  }
  __syncthreads();
  if (t <= E_) offs[t] = loff[t];
  for (int p = t; p < TK_; p += 256) {
    int e = sel[p];
    int pos = loff[e] + atomicAdd(&cur[e], 1);
    rows[pos] = p;
    inv[p] = pos;
  }
}

// ------------------------------------------------------- fc1 + swiglu ------
// Grid: x = 24 act-col tiles (32 act cols -> 64 weight cols: gate+up pair),
//       y = 8 experts * 32 row-slots of 64 permuted rows.
__global__ __launch_bounds__(256) void fc1_kernel(
    const float* __restrict__ X, const float* __restrict__ GUP,
    const int* __restrict__ offs, const int* __restrict__ rows,
    unsigned short* __restrict__ act) {
  __shared__ __align__(16) short As[64][40];  // [row][k], pad to 40
  __shared__ __align__(16) short Bs[64][40];  // [n][k]  (n: 0..31 gate, 32..63 up)

  int e    = blockIdx.y >> 5;
  int rbeg = offs[e], rend = offs[e + 1];
  int row0 = rbeg + (blockIdx.y & 31) * 64;
  if (row0 >= rend) return;
  int col0 = blockIdx.x * 32;

  int tid = threadIdx.x, lane = tid & 63, w = tid >> 6;

  // A staging: thread -> (row ar, k-chunk akc)
  int ar = tid >> 2, akc = (tid & 3) * 8;
  int aprow = row0 + ar;
  bool avalid = aprow < rend;
  const float* xrow = avalid ? (X + (size_t)(rows[aprow] >> 1) * H_) : X;

  // B staging: thread -> (col bn, k-octet bo); coalesced across lanes per j.
  int bn = tid & 63, bo = (tid >> 6) * 8;
  int gcol = (bn < 32) ? (col0 + bn) : (I_ + col0 + (bn - 32));
  const float* bbase = GUP + (size_t)e * H_ * GU_ + gcol;

  f32x4 acc[4] = {};

  for (int k0 = 0; k0 < H_; k0 += 32) {
    // stage A (fp32 -> bf16)
    float4 v0, v1;
    if (avalid) {
      const float4* p = (const float4*)(xrow + k0 + akc);
      v0 = p[0]; v1 = p[1];
    } else {
      v0 = make_float4(0.f, 0.f, 0.f, 0.f); v1 = v0;
    }
    short8 sv;
    sv[0] = f2bf(v0.x); sv[1] = f2bf(v0.y); sv[2] = f2bf(v0.z); sv[3] = f2bf(v0.w);
    sv[4] = f2bf(v1.x); sv[5] = f2bf(v1.y); sv[6] = f2bf(v1.z); sv[7] = f2bf(v1.w);
    *(short8*)&As[ar][akc] = sv;

    // stage B (column-per-lane, k-octet per wave)
    const float* bp = bbase + (size_t)(k0 + bo) * GU_;
    short8 bv;
#pragma unroll
    for (int j = 0; j < 8; ++j) bv[j] = f2bf(bp[(size_t)j * GU_]);
    *(short8*)&Bs[bn][bo] = bv;

    __syncthreads();

    bf16x8 af = *(const bf16x8*)&As[w * 16 + (lane & 15)][(lane >> 4) * 8];
#pragma unroll
    for (int nt = 0; nt < 4; ++nt) {
      bf16x8 bf = *(const bf16x8*)&Bs[nt * 16 + (lane & 15)][(lane >> 4) * 8];
      acc[nt] = __builtin_amdgcn_mfma_f32_16x16x32_bf16(af, bf, acc[nt], 0, 0, 0);
    }
    __syncthreads();
  }

  // epilogue: act = silu(gate) * up  (nt 0,1 = gate; nt+2 = up)
  int n = lane & 15, q = lane >> 4;
#pragma unroll
  for (int nt = 0; nt < 2; ++nt) {
#pragma unroll
    for (int r = 0; r < 4; ++r) {
      int prow = row0 + w * 16 + q * 4 + r;
      if (prow < rend) {
        float g = acc[nt][r], u = acc[nt + 2][r];
        float a = g / (1.0f + __expf(-g)) * u;
        act[(size_t)prow * I_ + col0 + nt * 16 + n] = (unsigned short)f2bf(a);
      }
    }
  }
}

// ----------------------------------------------------------------- fc2 -----
// Grid: x = 32 out-col tiles (64), y = 8 experts * 32 row-slots of 64.
__global__ __launch_bounds__(256) void fc2_kernel(
    const unsigned short* __restrict__ act, const float* __restrict__ DWN,
    const float* __restrict__ RW,
    const int* __restrict__ offs, const int* __restrict__ rows,
    float* __restrict__ fc2buf, float* __restrict__ outAtomic, int mode) {
  __shared__ __align__(16) short As[64][40];
  __shared__ __align__(16) short Bs[64][40];

  int e    = blockIdx.y >> 5;
  int rbeg = offs[e], rend = offs[e + 1];
  int row0 = rbeg + (blockIdx.y & 31) * 64;
  if (row0 >= rend) return;
  int col0 = blockIdx.x * 64;

  int tid = threadIdx.x, lane = tid & 63, w = tid >> 6;

  int ar = tid >> 2, akc = (tid & 3) * 8;
  int aprow = row0 + ar;
  bool avalid = aprow < rend;
  const unsigned short* arow = act + (size_t)(avalid ? aprow : row0) * I_;

  int bn = tid & 63, bo = (tid >> 6) * 8;
  const float* bbase = DWN + (size_t)e * I_ * H_ + col0 + bn;

  f32x4 acc[4] = {};

  for (int k0 = 0; k0 < I_; k0 += 32) {
    short8 av;
    if (avalid) av = *(const short8*)(arow + k0 + akc);
    else        av = (short8){0, 0, 0, 0, 0, 0, 0, 0};
    *(short8*)&As[ar][akc] = av;

    const float* bp = bbase + (size_t)(k0 + bo) * H_;
    short8 bv;
#pragma unroll
    for (int j = 0; j < 8; ++j) bv[j] = f2bf(bp[(size_t)j * H_]);
    *(short8*)&Bs[bn][bo] = bv;

    __syncthreads();

    bf16x8 af = *(const bf16x8*)&As[w * 16 + (lane & 15)][(lane >> 4) * 8];
#pragma unroll
    for (int nt = 0; nt < 4; ++nt) {
      bf16x8 bf = *(const bf16x8*)&Bs[nt * 16 + (lane & 15)][(lane >> 4) * 8];
      acc[nt] = __builtin_amdgcn_mfma_f32_16x16x32_bf16(af, bf, acc[nt], 0, 0, 0);
    }
    __syncthreads();
  }

  int n = lane & 15, q = lane >> 4;
  if (mode == 0) {
#pragma unroll
    for (int nt = 0; nt < 4; ++nt)
#pragma unroll
      for (int r = 0; r < 4; ++r) {
        int prow = row0 + w * 16 + q * 4 + r;
        if (prow < rend)
          fc2buf[(size_t)prow * H_ + col0 + nt * 16 + n] = acc[nt][r];
      }
  } else {
#pragma unroll
    for (int nt = 0; nt < 4; ++nt)
#pragma unroll
      for (int r = 0; r < 4; ++r) {
        int prow = row0 + w * 16 + q * 4 + r;
        if (prow < rend) {
          int pair = rows[prow];
          float rw = RW[pair];
          atomicAdd(&outAtomic[(size_t)(pair >> 1) * H_ + col0 + nt * 16 + n],
                    rw * acc[nt][r]);
        }
      }
  }
}

// ------------------------------------------------------------- combine -----
__global__ __launch_bounds__(256) void combine_kernel(
    const float* __restrict__ fc2buf, const float* __restrict__ RW,
    const int* __restrict__ inv, float* __restrict__ out) {
  int idx = blockIdx.x * 256 + threadIdx.x;   // T*512 threads, float4 each
  int t = idx >> 9, c4 = idx & 511;
  if (t >= T_) return;
  int r0 = inv[t * 2], r1 = inv[t * 2 + 1];
  float w0 = RW[t * 2], w1 = RW[t * 2 + 1];
  float4 v0 = ((const float4*)(fc2buf + (size_t)r0 * H_))[c4];
  float4 v1 = ((const float4*)(fc2buf + (size_t)r1 * H_))[c4];
  float4 o;
  o.x = w0 * v0.x + w1 * v1.x;
  o.y = w0 * v0.y + w1 * v1.y;
  o.z = w0 * v0.z + w1 * v1.z;
  o.w = w0 * v0.w + w1 * v1.w;
  ((float4*)(out + (size_t)t * H_))[c4] = o;
}

__global__ __launch_bounds__(256) void zero_kernel(float* __restrict__ out, int n) {
  int i = blockIdx.x * 256 + threadIdx.x;
  if (i < n) out[i] = 0.f;
}

// ------------------------------------------------------------- launcher ----
extern "C" void kernel_launch(void* const* d_in, const int* in_sizes, int n_in,
                              void* d_out, int out_size, void* d_ws, size_t ws_size,
                              hipStream_t stream) {
  const float* X   = (const float*)d_in[0];
  const float* RW  = (const float*)d_in[1];
  const float* GUP = (const float*)d_in[2];
  const float* DWN = (const float*)d_in[3];
  const int*   SEL = (const int*)d_in[4];
  float* out = (float*)d_out;

  char* ws = (char*)d_ws;
  int* offs = (int*)ws;                       // 16 ints
  int* rows = (int*)(ws + 64);                // 2048 ints
  int* inv  = (int*)(ws + 64 + 8192);         // 2048 ints
  unsigned short* act = (unsigned short*)(ws + 32768);          // 2048x768 bf16
  float* fc2buf = (float*)(ws + 32768 + (size_t)TK_ * I_ * 2);  // 2048x2048 f32
  size_t need = 32768 + (size_t)TK_ * I_ * 2 + (size_t)TK_ * H_ * 4;
  int mode = (ws_size >= need) ? 0 : 1;

  hipLaunchKernelGGL(route_kernel, dim3(1), dim3(256), 0, stream, SEL, offs, rows, inv);
  hipLaunchKernelGGL(fc1_kernel, dim3(24, 256), dim3(256), 0, stream,
                     X, GUP, offs, rows, act);
  if (mode == 1)
    hipLaunchKernelGGL(zero_kernel, dim3((T_ * H_ + 255) / 256), dim3(256), 0, stream,
                       out, T_ * H_);
  hipLaunchKernelGGL(fc2_kernel, dim3(32, 256), dim3(256), 0, stream,
                     act, DWN, RW, offs, rows, fc2buf, out, mode);
  if (mode == 0)
    hipLaunchKernelGGL(combine_kernel, dim3(T_ * 2), dim3(256), 0, stream,
                       fc2buf, RW, inv, out);
}

// Round 2
// 301.721 us; speedup vs baseline: 1.0619x; 1.0619x over previous
//
#include <hip/hip_runtime.h>
#include <math.h>

#define E_  8
#define H_  2048
#define I_  768
#define T_  1024
#define K_  2
#define TK_ 2048
#define GU_ 1536   // 2*I

typedef short  short8 __attribute__((ext_vector_type(8)));
typedef __bf16 bf16x8 __attribute__((ext_vector_type(8)));
typedef float  f32x4  __attribute__((ext_vector_type(4)));

static __device__ __forceinline__ short f2bf(float f) {
  union { float f; unsigned u; } v; v.f = f;
  unsigned r = (v.u + 0x7fffu + ((v.u >> 16) & 1u)) >> 16;
  return (short)r;
}

#define GLOAD_LDS16(g, l)                                                   \
  __builtin_amdgcn_global_load_lds(                                         \
      (const __attribute__((address_space(1))) void*)(g),                   \
      (__attribute__((address_space(3))) void*)(l), 16, 0, 0)

// ---------------------------------------------------------------- routing ---
__global__ __launch_bounds__(256) void route_kernel(
    const int* __restrict__ sel, int* __restrict__ offs,
    int* __restrict__ rows, int* __restrict__ inv) {
  __shared__ int cnt[E_], cur[E_], loff[E_ + 1];
  int t = threadIdx.x;
  if (t < E_) { cnt[t] = 0; cur[t] = 0; }
  __syncthreads();
  for (int p = t; p < TK_; p += 256) atomicAdd(&cnt[sel[p]], 1);
  __syncthreads();
  if (t == 0) {
    int s = 0;
    for (int e = 0; e < E_; ++e) { loff[e] = s; s += cnt[e]; }
    loff[E_] = s;
  }
  __syncthreads();
  if (t <= E_) offs[t] = loff[t];
  for (int p = t; p < TK_; p += 256) {
    int e = sel[p];
    int pos = loff[e] + atomicAdd(&cur[e], 1);
    rows[pos] = p;
    inv[p] = pos;
  }
}

// ------------------------------------------------------------ prep: X cast --
__global__ __launch_bounds__(256) void xcast_kernel(
    const float* __restrict__ X, unsigned short* __restrict__ Xb) {
  int i = blockIdx.x * 256 + threadIdx.x;       // one float4 each
  float4 v = ((const float4*)X)[i];
  ushort4 o;
  o.x = (unsigned short)f2bf(v.x); o.y = (unsigned short)f2bf(v.y);
  o.z = (unsigned short)f2bf(v.z); o.w = (unsigned short)f2bf(v.w);
  ((ushort4*)Xb)[i] = o;
}

// --------------------------------------- prep: weight transpose fp32->bf16 --
// src: [B][K][N] fp32  ->  dst: [B][N][K] bf16.  K,N multiples of 64.
__global__ __launch_bounds__(256) void wtrans_kernel(
    const float* __restrict__ src, unsigned short* __restrict__ dst,
    int K, int N) {
  __shared__ __align__(16) unsigned short tile[64][72];  // [n][k], pad 72
  int b  = blockIdx.z;
  int k0 = blockIdx.x * 64, n0 = blockIdx.y * 64;
  const float* s = src + (size_t)b * K * N;
  unsigned short* d = dst + (size_t)b * N * K;
  int t = threadIdx.x;
  int kr = t >> 4;             // 0..15
  int nc = (t & 15) * 4;       // 0..60
#pragma unroll
  for (int it = 0; it < 4; ++it) {
    int kk = kr + it * 16;
    float4 v = *(const float4*)(s + (size_t)(k0 + kk) * N + n0 + nc);
    tile[nc + 0][kk] = (unsigned short)f2bf(v.x);
    tile[nc + 1][kk] = (unsigned short)f2bf(v.y);
    tile[nc + 2][kk] = (unsigned short)f2bf(v.z);
    tile[nc + 3][kk] = (unsigned short)f2bf(v.w);
  }
  __syncthreads();
#pragma unroll
  for (int it = 0; it < 2; ++it) {
    int c = it * 256 + t;
    int onr = c >> 3, ok = (c & 7) * 8;
    short8 vv = *(const short8*)&tile[onr][ok];
    *(short8*)(d + (size_t)(n0 + onr) * K + k0 + ok) = vv;
  }
}

// --------------------------------------------------- fc1 (MFMA) + swiglu ----
// BM=64 rows, BN=128 weight cols (64 gate + 64 up, paired), BK=32.
// Grid: x = 12 (act-col tiles of 64), y = 8 experts * 32 row-slots.
__global__ __launch_bounds__(256) void fc1_mfma(
    const unsigned short* __restrict__ Xb, const unsigned short* __restrict__ GUPt,
    const int* __restrict__ offs, const int* __restrict__ rows,
    unsigned short* __restrict__ act) {
  __shared__ __align__(16) unsigned short As[64 * 32];   // [m][k]
  __shared__ __align__(16) unsigned short Bs[128 * 32];  // [r][k]; r<64 gate, r>=64 up

  int e    = blockIdx.y >> 5;
  int rbeg = offs[e], rend = offs[e + 1];
  int row0 = rbeg + (blockIdx.y & 31) * 64;
  if (row0 >= rend) return;
  int col0 = blockIdx.x * 64;                 // act columns [col0, col0+64)

  int tid = threadIdx.x, lane = tid & 63, w = tid >> 6;

  // A gather: wave w stages block rows [w*16, w*16+16); lane -> (row, k-octet)
  int ar   = w * 16 + (lane >> 2);
  int aidx = row0 + ar; if (aidx > rend - 1) aidx = rend - 1;
  int tok  = rows[aidx] >> 1;
  const unsigned short* agp = Xb + (size_t)tok * H_ + (lane & 3) * 8;
  unsigned short* aldst = As + w * 16 * 32;

  // B: wave w stages LDS rows [w*32, w*32+32) in 2 rounds of 16.
  const unsigned short* gupe = GUPt + (size_t)e * GU_ * H_;
  int br0 = w * 32 + (lane >> 2), br1 = br0 + 16;
  int n0g = (br0 < 64) ? (col0 + br0) : (I_ + col0 + br0 - 64);
  int n1g = (br1 < 64) ? (col0 + br1) : (I_ + col0 + br1 - 64);
  const unsigned short* bgp0 = gupe + (size_t)n0g * H_ + (lane & 3) * 8;
  const unsigned short* bgp1 = gupe + (size_t)n1g * H_ + (lane & 3) * 8;
  unsigned short* bldst0 = Bs + (w * 32) * 32;
  unsigned short* bldst1 = Bs + (w * 32 + 16) * 32;

  f32x4 acc[4][2] = {};
  int m = lane & 15, q = lane >> 4;

  for (int k0 = 0; k0 < H_; k0 += 32) {
    GLOAD_LDS16(agp  + k0, aldst);
    GLOAD_LDS16(bgp0 + k0, bldst0);
    GLOAD_LDS16(bgp1 + k0, bldst1);
    __syncthreads();
    bf16x8 af[4], bfr[2];
#pragma unroll
    for (int mt = 0; mt < 4; ++mt)
      af[mt] = *(const bf16x8*)(As + (mt * 16 + m) * 32 + q * 8);
    bfr[0] = *(const bf16x8*)(Bs + (w * 16 + m) * 32 + q * 8);
    bfr[1] = *(const bf16x8*)(Bs + (64 + w * 16 + m) * 32 + q * 8);
#pragma unroll
    for (int mt = 0; mt < 4; ++mt) {
      acc[mt][0] = __builtin_amdgcn_mfma_f32_16x16x32_bf16(af[mt], bfr[0], acc[mt][0], 0, 0, 0);
      acc[mt][1] = __builtin_amdgcn_mfma_f32_16x16x32_bf16(af[mt], bfr[1], acc[mt][1], 0, 0, 0);
    }
    __syncthreads();
  }

  // epilogue: act col = col0 + w*16 + (lane&15); C/D: col=lane&15, row=q*4+r
#pragma unroll
  for (int mt = 0; mt < 4; ++mt)
#pragma unroll
    for (int r = 0; r < 4; ++r) {
      int prow = row0 + mt * 16 + q * 4 + r;
      if (prow < rend) {
        float g = acc[mt][0][r], u = acc[mt][1][r];
        float a = g / (1.0f + __expf(-g)) * u;
        act[(size_t)prow * I_ + col0 + w * 16 + m] = (unsigned short)f2bf(a);
      }
    }
}

// ----------------------------------------------------------- fc2 (MFMA) -----
// BM=64, BN=128 out cols, BK=32. Grid: x = 16, y = 8*32 slots.
__global__ __launch_bounds__(256) void fc2_mfma(
    const unsigned short* __restrict__ act, const unsigned short* __restrict__ DWNt,
    const int* __restrict__ offs, float* __restrict__ fc2buf) {
  __shared__ __align__(16) unsigned short As[64 * 32];
  __shared__ __align__(16) unsigned short Bs[128 * 32];

  int e    = blockIdx.y >> 5;
  int rbeg = offs[e], rend = offs[e + 1];
  int row0 = rbeg + (blockIdx.y & 31) * 64;
  if (row0 >= rend) return;
  int col0 = blockIdx.x * 128;

  int tid = threadIdx.x, lane = tid & 63, w = tid >> 6;

  int ar   = w * 16 + (lane >> 2);
  int aidx = row0 + ar; if (aidx > TK_ - 1) aidx = TK_ - 1;
  const unsigned short* agp = act + (size_t)aidx * I_ + (lane & 3) * 8;
  unsigned short* aldst = As + w * 16 * 32;

  const unsigned short* dwe = DWNt + (size_t)e * H_ * I_;
  int br0 = w * 32 + (lane >> 2), br1 = br0 + 16;
  const unsigned short* bgp0 = dwe + (size_t)(col0 + br0) * I_ + (lane & 3) * 8;
  const unsigned short* bgp1 = dwe + (size_t)(col0 + br1) * I_ + (lane & 3) * 8;
  unsigned short* bldst0 = Bs + (w * 32) * 32;
  unsigned short* bldst1 = Bs + (w * 32 + 16) * 32;

  f32x4 acc[4][2] = {};
  int m = lane & 15, q = lane >> 4;

  for (int k0 = 0; k0 < I_; k0 += 32) {
    GLOAD_LDS16(agp  + k0, aldst);
    GLOAD_LDS16(bgp0 + k0, bldst0);
    GLOAD_LDS16(bgp1 + k0, bldst1);
    __syncthreads();
    bf16x8 af[4], bfr[2];
#pragma unroll
    for (int mt = 0; mt < 4; ++mt)
      af[mt] = *(const bf16x8*)(As + (mt * 16 + m) * 32 + q * 8);
    bfr[0] = *(const bf16x8*)(Bs + (w * 16 + m) * 32 + q * 8);
    bfr[1] = *(const bf16x8*)(Bs + (64 + w * 16 + m) * 32 + q * 8);
#pragma unroll
    for (int mt = 0; mt < 4; ++mt) {
      acc[mt][0] = __builtin_amdgcn_mfma_f32_16x16x32_bf16(af[mt], bfr[0], acc[mt][0], 0, 0, 0);
      acc[mt][1] = __builtin_amdgcn_mfma_f32_16x16x32_bf16(af[mt], bfr[1], acc[mt][1], 0, 0, 0);
    }
    __syncthreads();
  }

#pragma unroll
  for (int mt = 0; mt < 4; ++mt)
#pragma unroll
    for (int nf = 0; nf < 2; ++nf)
#pragma unroll
      for (int r = 0; r < 4; ++r) {
        int prow = row0 + mt * 16 + q * 4 + r;
        if (prow < rend)
          fc2buf[(size_t)prow * H_ + col0 + nf * 64 + w * 16 + m] = acc[mt][nf][r];
      }
}

// ------------------------------------------------------------- combine -----
__global__ __launch_bounds__(256) void combine_kernel(
    const float* __restrict__ fc2buf, const float* __restrict__ RW,
    const int* __restrict__ inv, float* __restrict__ out) {
  int idx = blockIdx.x * 256 + threadIdx.x;   // T*512 threads, float4 each
  int t = idx >> 9, c4 = idx & 511;
  if (t >= T_) return;
  int r0 = inv[t * 2], r1 = inv[t * 2 + 1];
  float w0 = RW[t * 2], w1 = RW[t * 2 + 1];
  float4 v0 = ((const float4*)(fc2buf + (size_t)r0 * H_))[c4];
  float4 v1 = ((const float4*)(fc2buf + (size_t)r1 * H_))[c4];
  float4 o;
  o.x = w0 * v0.x + w1 * v1.x;
  o.y = w0 * v0.y + w1 * v1.y;
  o.z = w0 * v0.z + w1 * v1.z;
  o.w = w0 * v0.w + w1 * v1.w;
  ((float4*)(out + (size_t)t * H_))[c4] = o;
}

// ========================= fallback path (round-1, proven) ==================
__global__ __launch_bounds__(256) void fc1_kernel(
    const float* __restrict__ X, const float* __restrict__ GUP,
    const int* __restrict__ offs, const int* __restrict__ rows,
    unsigned short* __restrict__ act) {
  __shared__ __align__(16) short As[64][40];
  __shared__ __align__(16) short Bs[64][40];
  int e    = blockIdx.y >> 5;
  int rbeg = offs[e], rend = offs[e + 1];
  int row0 = rbeg + (blockIdx.y & 31) * 64;
  if (row0 >= rend) return;
  int col0 = blockIdx.x * 32;
  int tid = threadIdx.x, lane = tid & 63, w = tid >> 6;
  int ar = tid >> 2, akc = (tid & 3) * 8;
  int aprow = row0 + ar;
  bool avalid = aprow < rend;
  const float* xrow = avalid ? (X + (size_t)(rows[aprow] >> 1) * H_) : X;
  int bn = tid & 63, bo = (tid >> 6) * 8;
  int gcol = (bn < 32) ? (col0 + bn) : (I_ + col0 + (bn - 32));
  const float* bbase = GUP + (size_t)e * H_ * GU_ + gcol;
  f32x4 acc[4] = {};
  for (int k0 = 0; k0 < H_; k0 += 32) {
    float4 v0, v1;
    if (avalid) {
      const float4* p = (const float4*)(xrow + k0 + akc);
      v0 = p[0]; v1 = p[1];
    } else { v0 = make_float4(0.f,0.f,0.f,0.f); v1 = v0; }
    short8 sv;
    sv[0]=f2bf(v0.x); sv[1]=f2bf(v0.y); sv[2]=f2bf(v0.z); sv[3]=f2bf(v0.w);
    sv[4]=f2bf(v1.x); sv[5]=f2bf(v1.y); sv[6]=f2bf(v1.z); sv[7]=f2bf(v1.w);
    *(short8*)&As[ar][akc] = sv;
    const float* bp = bbase + (size_t)(k0 + bo) * GU_;
    short8 bv;
#pragma unroll
    for (int j = 0; j < 8; ++j) bv[j] = f2bf(bp[(size_t)j * GU_]);
    *(short8*)&Bs[bn][bo] = bv;
    __syncthreads();
    bf16x8 af = *(const bf16x8*)&As[w * 16 + (lane & 15)][(lane >> 4) * 8];
#pragma unroll
    for (int nt = 0; nt < 4; ++nt) {
      bf16x8 bf = *(const bf16x8*)&Bs[nt * 16 + (lane & 15)][(lane >> 4) * 8];
      acc[nt] = __builtin_amdgcn_mfma_f32_16x16x32_bf16(af, bf, acc[nt], 0, 0, 0);
    }
    __syncthreads();
  }
  int n = lane & 15, q = lane >> 4;
#pragma unroll
  for (int nt = 0; nt < 2; ++nt)
#pragma unroll
    for (int r = 0; r < 4; ++r) {
      int prow = row0 + w * 16 + q * 4 + r;
      if (prow < rend) {
        float g = acc[nt][r], u = acc[nt + 2][r];
        float a = g / (1.0f + __expf(-g)) * u;
        act[(size_t)prow * I_ + col0 + nt * 16 + n] = (unsigned short)f2bf(a);
      }
    }
}

__global__ __launch_bounds__(256) void fc2_kernel(
    const unsigned short* __restrict__ act, const float* __restrict__ DWN,
    const float* __restrict__ RW,
    const int* __restrict__ offs, const int* __restrict__ rows,
    float* __restrict__ fc2buf, float* __restrict__ outAtomic, int mode) {
  __shared__ __align__(16) short As[64][40];
  __shared__ __align__(16) short Bs[64][40];
  int e    = blockIdx.y >> 5;
  int rbeg = offs[e], rend = offs[e + 1];
  int row0 = rbeg + (blockIdx.y & 31) * 64;
  if (row0 >= rend) return;
  int col0 = blockIdx.x * 64;
  int tid = threadIdx.x, lane = tid & 63, w = tid >> 6;
  int ar = tid >> 2, akc = (tid & 3) * 8;
  int aprow = row0 + ar;
  bool avalid = aprow < rend;
  const unsigned short* arow = act + (size_t)(avalid ? aprow : row0) * I_;
  int bn = tid & 63, bo = (tid >> 6) * 8;
  const float* bbase = DWN + (size_t)e * I_ * H_ + col0 + bn;
  f32x4 acc[4] = {};
  for (int k0 = 0; k0 < I_; k0 += 32) {
    short8 av;
    if (avalid) av = *(const short8*)(arow + k0 + akc);
    else        av = (short8){0,0,0,0,0,0,0,0};
    *(short8*)&As[ar][akc] = av;
    const float* bp = bbase + (size_t)(k0 + bo) * H_;
    short8 bv;
#pragma unroll
    for (int j = 0; j < 8; ++j) bv[j] = f2bf(bp[(size_t)j * H_]);
    *(short8*)&Bs[bn][bo] = bv;
    __syncthreads();
    bf16x8 af = *(const bf16x8*)&As[w * 16 + (lane & 15)][(lane >> 4) * 8];
#pragma unroll
    for (int nt = 0; nt < 4; ++nt) {
      bf16x8 bf = *(const bf16x8*)&Bs[nt * 16 + (lane & 15)][(lane >> 4) * 8];
      acc[nt] = __builtin_amdgcn_mfma_f32_16x16x32_bf16(af, bf, acc[nt], 0, 0, 0);
    }
    __syncthreads();
  }
  int n = lane & 15, q = lane >> 4;
  if (mode == 0) {
#pragma unroll
    for (int nt = 0; nt < 4; ++nt)
#pragma unroll
      for (int r = 0; r < 4; ++r) {
        int prow = row0 + w * 16 + q * 4 + r;
        if (prow < rend)
          fc2buf[(size_t)prow * H_ + col0 + nt * 16 + n] = acc[nt][r];
      }
  } else {
#pragma unroll
    for (int nt = 0; nt < 4; ++nt)
#pragma unroll
      for (int r = 0; r < 4; ++r) {
        int prow = row0 + w * 16 + q * 4 + r;
        if (prow < rend) {
          int pair = rows[prow];
          float rw = RW[pair];
          atomicAdd(&outAtomic[(size_t)(pair >> 1) * H_ + col0 + nt * 16 + n],
                    rw * acc[nt][r]);
        }
      }
  }
}

__global__ __launch_bounds__(256) void zero_kernel(float* __restrict__ out, int n) {
  int i = blockIdx.x * 256 + threadIdx.x;
  if (i < n) out[i] = 0.f;
}

// ------------------------------------------------------------- launcher ----
extern "C" void kernel_launch(void* const* d_in, const int* in_sizes, int n_in,
                              void* d_out, int out_size, void* d_ws, size_t ws_size,
                              hipStream_t stream) {
  const float* X   = (const float*)d_in[0];
  const float* RW  = (const float*)d_in[1];
  const float* GUP = (const float*)d_in[2];
  const float* DWN = (const float*)d_in[3];
  const int*   SEL = (const int*)d_in[4];
  float* out = (float*)d_out;

  char* ws = (char*)d_ws;
  // fast-path layout
  int* offs = (int*)ws;                              // 64 B
  int* rows = (int*)(ws + 1024);                     // 8 KB
  int* inv  = (int*)(ws + 16384);                    // 8 KB
  unsigned short* Xb   = (unsigned short*)(ws + 32768);
  unsigned short* GUPt = (unsigned short*)(ws + 32768 + 4194304);
  unsigned short* DWNt = (unsigned short*)(ws + 32768 + 4194304 + 50331648);
  unsigned short* act  = (unsigned short*)(ws + 32768 + 4194304 + 50331648 + 25165824);
  float* fc2buf = (float*)(ws + 32768 + 4194304 + 50331648 + 25165824 + 3145728);
  size_t fast_need = 32768ull + 4194304 + 50331648 + 25165824 + 3145728 + 16777216;

  hipLaunchKernelGGL(route_kernel, dim3(1), dim3(256), 0, stream, SEL, offs, rows, inv);

  if (ws_size >= fast_need) {
    hipLaunchKernelGGL(xcast_kernel, dim3(T_ * H_ / 4 / 256), dim3(256), 0, stream, X, Xb);
    hipLaunchKernelGGL(wtrans_kernel, dim3(H_ / 64, GU_ / 64, E_), dim3(256), 0, stream,
                       GUP, GUPt, H_, GU_);
    hipLaunchKernelGGL(wtrans_kernel, dim3(I_ / 64, H_ / 64, E_), dim3(256), 0, stream,
                       DWN, DWNt, I_, H_);
    hipLaunchKernelGGL(fc1_mfma, dim3(12, 256), dim3(256), 0, stream,
                       Xb, GUPt, offs, rows, act);
    hipLaunchKernelGGL(fc2_mfma, dim3(16, 256), dim3(256), 0, stream,
                       act, DWNt, offs, fc2buf);
    hipLaunchKernelGGL(combine_kernel, dim3(T_ * 2), dim3(256), 0, stream,
                       fc2buf, RW, inv, out);
  } else {
    // fallback: round-1 path
    unsigned short* act2 = (unsigned short*)(ws + 32768);
    float* fc2buf2 = (float*)(ws + 32768 + (size_t)TK_ * I_ * 2);
    size_t need = 32768 + (size_t)TK_ * I_ * 2 + (size_t)TK_ * H_ * 4;
    int mode = (ws_size >= need) ? 0 : 1;
    hipLaunchKernelGGL(fc1_kernel, dim3(24, 256), dim3(256), 0, stream,
                       X, GUP, offs, rows, act2);
    if (mode == 1)
      hipLaunchKernelGGL(zero_kernel, dim3((T_ * H_ + 255) / 256), dim3(256), 0, stream,
                         out, T_ * H_);
    hipLaunchKernelGGL(fc2_kernel, dim3(32, 256), dim3(256), 0, stream,
                       act2, DWN, RW, offs, rows, fc2buf2, out, mode);
    if (mode == 0)
      hipLaunchKernelGGL(combine_kernel, dim3(T_ * 2), dim3(256), 0, stream,
                         fc2buf2, RW, inv, out);
  }
}

// Round 3
// 264.696 us; speedup vs baseline: 1.2104x; 1.1399x over previous
//
#include <hip/hip_runtime.h>
#include <math.h>

#define E_  8
#define H_  2048
#define I_  768
#define T_  1024
#define K_  2
#define TK_ 2048
#define GU_ 1536   // 2*I

typedef short  short8 __attribute__((ext_vector_type(8)));
typedef __bf16 bf16x8 __attribute__((ext_vector_type(8)));
typedef float  f32x4  __attribute__((ext_vector_type(4)));

static __device__ __forceinline__ short f2bf(float f) {
  union { float f; unsigned u; } v; v.f = f;
  unsigned r = (v.u + 0x7fffu + ((v.u >> 16) & 1u)) >> 16;
  return (short)r;
}

// pack two floats -> two bf16 in one u32 (round-half-up + v_perm)
static __device__ __forceinline__ unsigned pk2bf(float a, float b) {
  unsigned ua = __float_as_uint(a) + 0x8000u;
  unsigned ub = __float_as_uint(b) + 0x8000u;
  return __builtin_amdgcn_perm(ub, ua, 0x07060302u);  // lo=hi16(ua), hi=hi16(ub)
}

#define GLOAD_LDS16(g, l)                                                   \
  __builtin_amdgcn_global_load_lds(                                         \
      (const __attribute__((address_space(1))) void*)(g),                   \
      (__attribute__((address_space(3))) void*)(l), 16, 0, 0)

#define MFMA_BF16_16x16x32 __builtin_amdgcn_mfma_f32_16x16x32_bf16

// swizzled fragment read: row-major [row][64k], phys octet = oct ^ (row&7)
static __device__ __forceinline__ bf16x8 frag_ld(const unsigned short* base,
                                                 int row, int oct) {
  return *(const bf16x8*)(base + row * 64 + ((oct ^ (row & 7)) * 8));
}

// ---------------------------------------------------------------- routing ---
__global__ __launch_bounds__(256) void route_kernel(
    const int* __restrict__ sel, int* __restrict__ offs,
    int* __restrict__ rows, int* __restrict__ inv) {
  __shared__ int cnt[E_], cur[E_], loff[E_ + 1];
  int t = threadIdx.x;
  if (t < E_) { cnt[t] = 0; cur[t] = 0; }
  __syncthreads();
  for (int p = t; p < TK_; p += 256) atomicAdd(&cnt[sel[p]], 1);
  __syncthreads();
  if (t == 0) {
    int s = 0;
    for (int e = 0; e < E_; ++e) { loff[e] = s; s += cnt[e]; }
    loff[E_] = s;
  }
  __syncthreads();
  if (t <= E_) offs[t] = loff[t];
  for (int p = t; p < TK_; p += 256) {
    int e = sel[p];
    int pos = loff[e] + atomicAdd(&cur[e], 1);
    rows[pos] = p;
    inv[p] = pos;
  }
}

// ------------------------------------------------------------ prep: X cast --
__global__ __launch_bounds__(256) void xcast_kernel(
    const float* __restrict__ X, unsigned short* __restrict__ Xb) {
  int i = blockIdx.x * 256 + threadIdx.x;       // one float4 each
  float4 v = ((const float4*)X)[i];
  unsigned p0 = pk2bf(v.x, v.y), p1 = pk2bf(v.z, v.w);
  ((uint2*)Xb)[i] = make_uint2(p0, p1);
}

// --------------------------------------- prep: weight transpose fp32->bf16 --
// src: [B][K][N] fp32  ->  dst: [B][N][K] bf16.  K,N multiples of 64.
// LDS tile [n][k] 64x64 bf16, quad (4k=8B) positions XOR-swizzled by n.
__global__ __launch_bounds__(256) void wtrans_kernel(
    const float* __restrict__ src, unsigned short* __restrict__ dst,
    int K, int N) {
  __shared__ __align__(16) unsigned short tile[64 * 64];
  int b  = blockIdx.z;
  int k0 = blockIdx.x * 64, n0 = blockIdx.y * 64;
  const float* s = src + (size_t)b * K * N + (size_t)k0 * N + n0;
  unsigned short* d = dst + (size_t)b * N * K + (size_t)n0 * K + k0;
  int t = threadIdx.x;
  int kq = (t >> 4) * 4;        // k base 0..60 (4 consecutive k per thread)
  int nq = (t & 15) * 4;        // n base 0..60 (4 consecutive n per thread)
  float4 v[4];
#pragma unroll
  for (int i = 0; i < 4; ++i)
    v[i] = *(const float4*)(s + (size_t)(kq + i) * N + nq);
  int qlog = kq >> 2;           // quad index 0..15
#pragma unroll
  for (int j = 0; j < 4; ++j) {
    int n = nq + j;
    unsigned p0 = pk2bf(((const float*)&v[0])[j], ((const float*)&v[1])[j]);
    unsigned p1 = pk2bf(((const float*)&v[2])[j], ((const float*)&v[3])[j]);
    int qphys = qlog ^ (n & 15);
    *(uint2*)(tile + n * 64 + qphys * 4) = make_uint2(p0, p1);
  }
  __syncthreads();
  int r = t >> 2;
#pragma unroll
  for (int p = 0; p < 2; ++p) {
    int q0 = (t & 3) * 4 + p * 2;               // quad pair (q0, q0+1)
    uint2 a_ = *(const uint2*)(tile + r * 64 + ((q0 ^ (r & 15)) * 4));
    uint2 b2 = *(const uint2*)(tile + r * 64 + (((q0 + 1) ^ (r & 15)) * 4));
    *(uint4*)(d + (size_t)r * K + q0 * 4) = make_uint4(a_.x, a_.y, b2.x, b2.y);
  }
}

// --------------------------------------------------- fc1 (MFMA) + swiglu ----
// BM=64 rows, 32 act cols (32 gate + 32 up weight rows), BK=64, double-buffer.
// Grid: x = 24 (act-col tiles of 32), y = 8 experts * 32 row-slots.
__global__ __launch_bounds__(256) void fc1_mfma(
    const unsigned short* __restrict__ Xb, const unsigned short* __restrict__ GUPt,
    const int* __restrict__ offs, const int* __restrict__ rows,
    unsigned short* __restrict__ act) {
  __shared__ __align__(16) unsigned short As[2][64 * 64];
  __shared__ __align__(16) unsigned short Bs[2][64 * 64];

  int e    = blockIdx.y >> 5;
  int rbeg = offs[e], rend = offs[e + 1];
  int row0 = rbeg + (blockIdx.y & 31) * 64;
  if (row0 >= rend) return;
  int c0 = blockIdx.x * 32;

  int tid = threadIdx.x, lane = tid & 63, w = tid >> 6;
  int rl  = lane >> 3;                    // 0..7
  int oct = (lane & 7) ^ rl;              // swizzled logical k-octet to fetch

  // A: wave w stages rows w*16 .. w*16+15 (two glls of 8 rows each), gathered.
  int arow0 = row0 + w * 16 + rl, arow1 = arow0 + 8;
  int aidx0 = arow0 < rend ? arow0 : rend - 1;
  int aidx1 = arow1 < rend ? arow1 : rend - 1;
  const unsigned short* agp0 = Xb + (size_t)(rows[aidx0] >> 1) * H_ + oct * 8;
  const unsigned short* agp1 = Xb + (size_t)(rows[aidx1] >> 1) * H_ + oct * 8;

  // B: Bs row br<32 -> gate col c0+br ; br>=32 -> up col I_+c0+br-32.
  const unsigned short* gupe = GUPt + (size_t)e * GU_ * H_;
  int br0 = w * 16 + rl, br1 = br0 + 8;
  int n0 = (br0 < 32) ? (c0 + br0) : (I_ + c0 + br0 - 32);
  int n1 = (br1 < 32) ? (c0 + br1) : (I_ + c0 + br1 - 32);
  const unsigned short* bgp0 = gupe + (size_t)n0 * H_ + oct * 8;
  const unsigned short* bgp1 = gupe + (size_t)n1 * H_ + oct * 8;

  auto issue = [&](int buf, int k0) {
    GLOAD_LDS16(agp0 + k0, &As[buf][0] + (w * 16) * 64);
    GLOAD_LDS16(agp1 + k0, &As[buf][0] + (w * 16 + 8) * 64);
    GLOAD_LDS16(bgp0 + k0, &Bs[buf][0] + (w * 16) * 64);
    GLOAD_LDS16(bgp1 + k0, &Bs[buf][0] + (w * 16 + 8) * 64);
  };

  int mh = w >> 1, nh = w & 1;
  int m = lane & 15, q = lane >> 4;
  f32x4 acc[2][2] = {};

  issue(0, 0);
  int cur = 0;
  const int niter = H_ / 64;
#pragma unroll 1
  for (int it = 0; it < niter; ++it) {
    __syncthreads();                       // drains vmcnt -> buf[cur] ready
    if (it + 1 < niter) issue(cur ^ 1, (it + 1) * 64);
    const unsigned short* a_ = &As[cur][0];
    const unsigned short* b_ = &Bs[cur][0];
#pragma unroll
    for (int kk = 0; kk < 2; ++kk) {
      bf16x8 af0 = frag_ld(a_, mh * 32 + m,      kk * 4 + q);
      bf16x8 af1 = frag_ld(a_, mh * 32 + 16 + m, kk * 4 + q);
      bf16x8 bg  = frag_ld(b_, nh * 16 + m,      kk * 4 + q);
      bf16x8 bu  = frag_ld(b_, 32 + nh * 16 + m, kk * 4 + q);
      acc[0][0] = MFMA_BF16_16x16x32(af0, bg, acc[0][0], 0, 0, 0);
      acc[0][1] = MFMA_BF16_16x16x32(af0, bu, acc[0][1], 0, 0, 0);
      acc[1][0] = MFMA_BF16_16x16x32(af1, bg, acc[1][0], 0, 0, 0);
      acc[1][1] = MFMA_BF16_16x16x32(af1, bu, acc[1][1], 0, 0, 0);
    }
    cur ^= 1;
  }

  // epilogue: act = silu(gate)*up ; C/D: col=lane&15, row=q*4+r
#pragma unroll
  for (int mt = 0; mt < 2; ++mt)
#pragma unroll
    for (int r = 0; r < 4; ++r) {
      int prow = row0 + mh * 32 + mt * 16 + q * 4 + r;
      if (prow < rend) {
        float g = acc[mt][0][r], u = acc[mt][1][r];
        float a = g / (1.0f + __expf(-g)) * u;
        act[(size_t)prow * I_ + c0 + nh * 16 + m] = (unsigned short)f2bf(a);
      }
    }
}

// ----------------------------------------------------------- fc2 (MFMA) -----
// BM=64, BN=64 out cols, BK=64, double-buffer. Grid: x = 32, y = 8*32 slots.
__global__ __launch_bounds__(256) void fc2_mfma(
    const unsigned short* __restrict__ act, const unsigned short* __restrict__ DWNt,
    const int* __restrict__ offs, float* __restrict__ fc2buf) {
  __shared__ __align__(16) unsigned short As[2][64 * 64];
  __shared__ __align__(16) unsigned short Bs[2][64 * 64];

  int e    = blockIdx.y >> 5;
  int rbeg = offs[e], rend = offs[e + 1];
  int row0 = rbeg + (blockIdx.y & 31) * 64;
  if (row0 >= rend) return;
  int c0 = blockIdx.x * 64;

  int tid = threadIdx.x, lane = tid & 63, w = tid >> 6;
  int rl  = lane >> 3;
  int oct = (lane & 7) ^ rl;

  int arow0 = row0 + w * 16 + rl, arow1 = arow0 + 8;
  int aidx0 = arow0 < rend ? arow0 : rend - 1;
  int aidx1 = arow1 < rend ? arow1 : rend - 1;
  const unsigned short* agp0 = act + (size_t)aidx0 * I_ + oct * 8;
  const unsigned short* agp1 = act + (size_t)aidx1 * I_ + oct * 8;

  const unsigned short* dwe = DWNt + (size_t)e * H_ * I_;
  const unsigned short* bgp0 = dwe + (size_t)(c0 + w * 16 + rl) * I_ + oct * 8;
  const unsigned short* bgp1 = dwe + (size_t)(c0 + w * 16 + rl + 8) * I_ + oct * 8;

  auto issue = [&](int buf, int k0) {
    GLOAD_LDS16(agp0 + k0, &As[buf][0] + (w * 16) * 64);
    GLOAD_LDS16(agp1 + k0, &As[buf][0] + (w * 16 + 8) * 64);
    GLOAD_LDS16(bgp0 + k0, &Bs[buf][0] + (w * 16) * 64);
    GLOAD_LDS16(bgp1 + k0, &Bs[buf][0] + (w * 16 + 8) * 64);
  };

  int mh = w >> 1, nh = w & 1;
  int m = lane & 15, q = lane >> 4;
  f32x4 acc[2][2] = {};

  issue(0, 0);
  int cur = 0;
  const int niter = I_ / 64;
#pragma unroll 1
  for (int it = 0; it < niter; ++it) {
    __syncthreads();
    if (it + 1 < niter) issue(cur ^ 1, (it + 1) * 64);
    const unsigned short* a_ = &As[cur][0];
    const unsigned short* b_ = &Bs[cur][0];
#pragma unroll
    for (int kk = 0; kk < 2; ++kk) {
      bf16x8 af0 = frag_ld(a_, mh * 32 + m,          kk * 4 + q);
      bf16x8 af1 = frag_ld(a_, mh * 32 + 16 + m,     kk * 4 + q);
      bf16x8 bf0 = frag_ld(b_, nh * 32 + m,          kk * 4 + q);
      bf16x8 bf1 = frag_ld(b_, nh * 32 + 16 + m,     kk * 4 + q);
      acc[0][0] = MFMA_BF16_16x16x32(af0, bf0, acc[0][0], 0, 0, 0);
      acc[0][1] = MFMA_BF16_16x16x32(af0, bf1, acc[0][1], 0, 0, 0);
      acc[1][0] = MFMA_BF16_16x16x32(af1, bf0, acc[1][0], 0, 0, 0);
      acc[1][1] = MFMA_BF16_16x16x32(af1, bf1, acc[1][1], 0, 0, 0);
    }
    cur ^= 1;
  }

#pragma unroll
  for (int mt = 0; mt < 2; ++mt)
#pragma unroll
    for (int nt = 0; nt < 2; ++nt)
#pragma unroll
      for (int r = 0; r < 4; ++r) {
        int prow = row0 + mh * 32 + mt * 16 + q * 4 + r;
        if (prow < rend)
          fc2buf[(size_t)prow * H_ + c0 + nh * 32 + nt * 16 + m] = acc[mt][nt][r];
      }
}

// ------------------------------------------------------------- combine -----
__global__ __launch_bounds__(256) void combine_kernel(
    const float* __restrict__ fc2buf, const float* __restrict__ RW,
    const int* __restrict__ inv, float* __restrict__ out) {
  int idx = blockIdx.x * 256 + threadIdx.x;   // T*512 threads, float4 each
  int t = idx >> 9, c4 = idx & 511;
  if (t >= T_) return;
  int r0 = inv[t * 2], r1 = inv[t * 2 + 1];
  float w0 = RW[t * 2], w1 = RW[t * 2 + 1];
  float4 v0 = ((const float4*)(fc2buf + (size_t)r0 * H_))[c4];
  float4 v1 = ((const float4*)(fc2buf + (size_t)r1 * H_))[c4];
  float4 o;
  o.x = w0 * v0.x + w1 * v1.x;
  o.y = w0 * v0.y + w1 * v1.y;
  o.z = w0 * v0.z + w1 * v1.z;
  o.w = w0 * v0.w + w1 * v1.w;
  ((float4*)(out + (size_t)t * H_))[c4] = o;
}

// ========================= fallback path (round-1, proven) ==================
__global__ __launch_bounds__(256) void fc1_kernel(
    const float* __restrict__ X, const float* __restrict__ GUP,
    const int* __restrict__ offs, const int* __restrict__ rows,
    unsigned short* __restrict__ act) {
  __shared__ __align__(16) short As[64][40];
  __shared__ __align__(16) short Bs[64][40];
  int e    = blockIdx.y >> 5;
  int rbeg = offs[e], rend = offs[e + 1];
  int row0 = rbeg + (blockIdx.y & 31) * 64;
  if (row0 >= rend) return;
  int col0 = blockIdx.x * 32;
  int tid = threadIdx.x, lane = tid & 63, w = tid >> 6;
  int ar = tid >> 2, akc = (tid & 3) * 8;
  int aprow = row0 + ar;
  bool avalid = aprow < rend;
  const float* xrow = avalid ? (X + (size_t)(rows[aprow] >> 1) * H_) : X;
  int bn = tid & 63, bo = (tid >> 6) * 8;
  int gcol = (bn < 32) ? (col0 + bn) : (I_ + col0 + (bn - 32));
  const float* bbase = GUP + (size_t)e * H_ * GU_ + gcol;
  f32x4 acc[4] = {};
  for (int k0 = 0; k0 < H_; k0 += 32) {
    float4 v0, v1;
    if (avalid) {
      const float4* p = (const float4*)(xrow + k0 + akc);
      v0 = p[0]; v1 = p[1];
    } else { v0 = make_float4(0.f,0.f,0.f,0.f); v1 = v0; }
    short8 sv;
    sv[0]=f2bf(v0.x); sv[1]=f2bf(v0.y); sv[2]=f2bf(v0.z); sv[3]=f2bf(v0.w);
    sv[4]=f2bf(v1.x); sv[5]=f2bf(v1.y); sv[6]=f2bf(v1.z); sv[7]=f2bf(v1.w);
    *(short8*)&As[ar][akc] = sv;
    const float* bp = bbase + (size_t)(k0 + bo) * GU_;
    short8 bv;
#pragma unroll
    for (int j = 0; j < 8; ++j) bv[j] = f2bf(bp[(size_t)j * GU_]);
    *(short8*)&Bs[bn][bo] = bv;
    __syncthreads();
    bf16x8 af = *(const bf16x8*)&As[w * 16 + (lane & 15)][(lane >> 4) * 8];
#pragma unroll
    for (int nt = 0; nt < 4; ++nt) {
      bf16x8 bf = *(const bf16x8*)&Bs[nt * 16 + (lane & 15)][(lane >> 4) * 8];
      acc[nt] = MFMA_BF16_16x16x32(af, bf, acc[nt], 0, 0, 0);
    }
    __syncthreads();
  }
  int n = lane & 15, q = lane >> 4;
#pragma unroll
  for (int nt = 0; nt < 2; ++nt)
#pragma unroll
    for (int r = 0; r < 4; ++r) {
      int prow = row0 + w * 16 + q * 4 + r;
      if (prow < rend) {
        float g = acc[nt][r], u = acc[nt + 2][r];
        float a = g / (1.0f + __expf(-g)) * u;
        act[(size_t)prow * I_ + col0 + nt * 16 + n] = (unsigned short)f2bf(a);
      }
    }
}

__global__ __launch_bounds__(256) void fc2_kernel(
    const unsigned short* __restrict__ act, const float* __restrict__ DWN,
    const float* __restrict__ RW,
    const int* __restrict__ offs, const int* __restrict__ rows,
    float* __restrict__ fc2buf, float* __restrict__ outAtomic, int mode) {
  __shared__ __align__(16) short As[64][40];
  __shared__ __align__(16) short Bs[64][40];
  int e    = blockIdx.y >> 5;
  int rbeg = offs[e], rend = offs[e + 1];
  int row0 = rbeg + (blockIdx.y & 31) * 64;
  if (row0 >= rend) return;
  int col0 = blockIdx.x * 64;
  int tid = threadIdx.x, lane = tid & 63, w = tid >> 6;
  int ar = tid >> 2, akc = (tid & 3) * 8;
  int aprow = row0 + ar;
  bool avalid = aprow < rend;
  const unsigned short* arow = act + (size_t)(avalid ? aprow : row0) * I_;
  int bn = tid & 63, bo = (tid >> 6) * 8;
  const float* bbase = DWN + (size_t)e * I_ * H_ + col0 + bn;
  f32x4 acc[4] = {};
  for (int k0 = 0; k0 < I_; k0 += 32) {
    short8 av;
    if (avalid) av = *(const short8*)(arow + k0 + akc);
    else        av = (short8){0,0,0,0,0,0,0,0};
    *(short8*)&As[ar][akc] = av;
    const float* bp = bbase + (size_t)(k0 + bo) * H_;
    short8 bv;
#pragma unroll
    for (int j = 0; j < 8; ++j) bv[j] = f2bf(bp[(size_t)j * H_]);
    *(short8*)&Bs[bn][bo] = bv;
    __syncthreads();
    bf16x8 af = *(const bf16x8*)&As[w * 16 + (lane & 15)][(lane >> 4) * 8];
#pragma unroll
    for (int nt = 0; nt < 4; ++nt) {
      bf16x8 bf = *(const bf16x8*)&Bs[nt * 16 + (lane & 15)][(lane >> 4) * 8];
      acc[nt] = MFMA_BF16_16x16x32(af, bf, acc[nt], 0, 0, 0);
    }
    __syncthreads();
  }
  int n = lane & 15, q = lane >> 4;
  if (mode == 0) {
#pragma unroll
    for (int nt = 0; nt < 4; ++nt)
#pragma unroll
      for (int r = 0; r < 4; ++r) {
        int prow = row0 + w * 16 + q * 4 + r;
        if (prow < rend)
          fc2buf[(size_t)prow * H_ + col0 + nt * 16 + n] = acc[nt][r];
      }
  } else {
#pragma unroll
    for (int nt = 0; nt < 4; ++nt)
#pragma unroll
      for (int r = 0; r < 4; ++r) {
        int prow = row0 + w * 16 + q * 4 + r;
        if (prow < rend) {
          int pair = rows[prow];
          float rw = RW[pair];
          atomicAdd(&outAtomic[(size_t)(pair >> 1) * H_ + col0 + nt * 16 + n],
                    rw * acc[nt][r]);
        }
      }
  }
}

__global__ __launch_bounds__(256) void zero_kernel(float* __restrict__ out, int n) {
  int i = blockIdx.x * 256 + threadIdx.x;
  if (i < n) out[i] = 0.f;
}

// ------------------------------------------------------------- launcher ----
extern "C" void kernel_launch(void* const* d_in, const int* in_sizes, int n_in,
                              void* d_out, int out_size, void* d_ws, size_t ws_size,
                              hipStream_t stream) {
  const float* X   = (const float*)d_in[0];
  const float* RW  = (const float*)d_in[1];
  const float* GUP = (const float*)d_in[2];
  const float* DWN = (const float*)d_in[3];
  const int*   SEL = (const int*)d_in[4];
  float* out = (float*)d_out;

  char* ws = (char*)d_ws;
  int* offs = (int*)ws;                              // 64 B
  int* rows = (int*)(ws + 1024);                     // 8 KB
  int* inv  = (int*)(ws + 16384);                    // 8 KB
  unsigned short* Xb   = (unsigned short*)(ws + 32768);
  unsigned short* GUPt = (unsigned short*)(ws + 32768 + 4194304);
  unsigned short* DWNt = (unsigned short*)(ws + 32768 + 4194304 + 50331648);
  unsigned short* act  = (unsigned short*)(ws + 32768 + 4194304 + 50331648 + 25165824);
  float* fc2buf = (float*)(ws + 32768 + 4194304 + 50331648 + 25165824 + 3145728);
  size_t fast_need = 32768ull + 4194304 + 50331648 + 25165824 + 3145728 + 16777216;

  hipLaunchKernelGGL(route_kernel, dim3(1), dim3(256), 0, stream, SEL, offs, rows, inv);

  if (ws_size >= fast_need) {
    hipLaunchKernelGGL(xcast_kernel, dim3(T_ * H_ / 4 / 256), dim3(256), 0, stream, X, Xb);
    hipLaunchKernelGGL(wtrans_kernel, dim3(H_ / 64, GU_ / 64, E_), dim3(256), 0, stream,
                       GUP, GUPt, H_, GU_);
    hipLaunchKernelGGL(wtrans_kernel, dim3(I_ / 64, H_ / 64, E_), dim3(256), 0, stream,
                       DWN, DWNt, I_, H_);
    hipLaunchKernelGGL(fc1_mfma, dim3(24, 256), dim3(256), 0, stream,
                       Xb, GUPt, offs, rows, act);
    hipLaunchKernelGGL(fc2_mfma, dim3(32, 256), dim3(256), 0, stream,
                       act, DWNt, offs, fc2buf);
    hipLaunchKernelGGL(combine_kernel, dim3(T_ * 2), dim3(256), 0, stream,
                       fc2buf, RW, inv, out);
  } else {
    unsigned short* act2 = (unsigned short*)(ws + 32768);
    float* fc2buf2 = (float*)(ws + 32768 + (size_t)TK_ * I_ * 2);
    size_t need = 32768 + (size_t)TK_ * I_ * 2 + (size_t)TK_ * H_ * 4;
    int mode = (ws_size >= need) ? 0 : 1;
    hipLaunchKernelGGL(fc1_kernel, dim3(24, 256), dim3(256), 0, stream,
                       X, GUP, offs, rows, act2);
    if (mode == 1)
      hipLaunchKernelGGL(zero_kernel, dim3((T_ * H_ + 255) / 256), dim3(256), 0, stream,
                         out, T_ * H_);
    hipLaunchKernelGGL(fc2_kernel, dim3(32, 256), dim3(256), 0, stream,
                       act2, DWN, RW, offs, rows, fc2buf2, out, mode);
    if (mode == 0)
      hipLaunchKernelGGL(combine_kernel, dim3(T_ * 2), dim3(256), 0, stream,
                         fc2buf2, RW, inv, out);
  }
}

// Round 4
// 257.549 us; speedup vs baseline: 1.2440x; 1.0278x over previous
//
#include <hip/hip_runtime.h>
#include <math.h>

#define E_  8
#define H_  2048
#define I_  768
#define T_  1024
#define K_  2
#define TK_ 2048
#define GU_ 1536   // 2*I

typedef short  short8 __attribute__((ext_vector_type(8)));
typedef __bf16 bf16x8 __attribute__((ext_vector_type(8)));
typedef float  f32x4  __attribute__((ext_vector_type(4)));

static __device__ __forceinline__ short f2bf(float f) {
  union { float f; unsigned u; } v; v.f = f;
  unsigned r = (v.u + 0x7fffu + ((v.u >> 16) & 1u)) >> 16;
  return (short)r;
}

// pack two floats -> two bf16 in one u32 (round-half-up + v_perm)
static __device__ __forceinline__ unsigned pk2bf(float a, float b) {
  unsigned ua = __float_as_uint(a) + 0x8000u;
  unsigned ub = __float_as_uint(b) + 0x8000u;
  return __builtin_amdgcn_perm(ub, ua, 0x07060302u);  // lo=hi16(ua), hi=hi16(ub)
}

#define GLOAD_LDS16(g, l)                                                   \
  __builtin_amdgcn_global_load_lds(                                         \
      (const __attribute__((address_space(1))) void*)(g),                   \
      (__attribute__((address_space(3))) void*)(l), 16, 0, 0)

#define MFMA_BF16_16x16x32 __builtin_amdgcn_mfma_f32_16x16x32_bf16

// swizzled fragment read: row-major [row][64k], phys octet = oct ^ (row&7)
static __device__ __forceinline__ bf16x8 frag_ld(const unsigned short* base,
                                                 int row, int oct) {
  return *(const bf16x8*)(base + row * 64 + ((oct ^ (row & 7)) * 8));
}

// swizzled quad write (4 bf16 = one k-quad q at LDS row n), matching frag_ld:
// oct = q>>1 -> phys oct = (q>>1)^(n&7); parity q&1 selects quad in octet.
static __device__ __forceinline__ void quad_st(unsigned short* base, int n,
                                               int q, unsigned u0, unsigned u1) {
  int off = n * 64 + (((q >> 1) ^ (n & 7)) * 8) + (q & 1) * 4;
  *(uint2*)(base + off) = make_uint2(u0, u1);
}

// ------------------------------------------------- prep: X cast + routing ---
__global__ __launch_bounds__(256) void prep_kernel(
    const float* __restrict__ X, unsigned short* __restrict__ Xb,
    const int* __restrict__ sel, int* __restrict__ offs,
    int* __restrict__ rows, int* __restrict__ inv) {
  __shared__ int cnt[E_], cur[E_], loff[E_ + 1];
  if (blockIdx.x < 2048) {
    int i = blockIdx.x * 256 + threadIdx.x;     // one float4 each
    float4 v = ((const float4*)X)[i];
    unsigned p0 = pk2bf(v.x, v.y), p1 = pk2bf(v.z, v.w);
    ((uint2*)Xb)[i] = make_uint2(p0, p1);
    return;
  }
  int t = threadIdx.x;
  if (t < E_) { cnt[t] = 0; cur[t] = 0; }
  __syncthreads();
  for (int p = t; p < TK_; p += 256) atomicAdd(&cnt[sel[p]], 1);
  __syncthreads();
  if (t == 0) {
    int s = 0;
    for (int e = 0; e < E_; ++e) { loff[e] = s; s += cnt[e]; }
    loff[E_] = s;
  }
  __syncthreads();
  if (t <= E_) offs[t] = loff[t];
  for (int p = t; p < TK_; p += 256) {
    int e = sel[p];
    int pos = loff[e] + atomicAdd(&cur[e], 1);
    rows[pos] = p;
    inv[p] = pos;
  }
}

// --------------------------------------------------- fc1 (MFMA) + swiglu ----
// BM=64 rows, 32 act cols (32 gate + 32 up weight cols), BK=64, double-buffer.
// A: bf16 via global_load_lds (gathered rows). B: fp32 direct from GUP
// ([k][n] layout), transposed+cast to bf16 in-LDS each iter.
// Grid: x = 24 (act-col tiles of 32), y = 8 experts * 32 row-slots.
__global__ __launch_bounds__(256) void fc1_mfma(
    const unsigned short* __restrict__ Xb, const float* __restrict__ GUP,
    const int* __restrict__ offs, const int* __restrict__ rows,
    unsigned short* __restrict__ act) {
  __shared__ __align__(16) unsigned short As[2][64 * 64];
  __shared__ __align__(16) unsigned short Bs[2][64 * 64];

  int e    = blockIdx.y >> 5;
  int rbeg = offs[e], rend = offs[e + 1];
  int row0 = rbeg + (blockIdx.y & 31) * 64;
  if (row0 >= rend) return;
  int c0 = blockIdx.x * 32;

  int tid = threadIdx.x, lane = tid & 63, w = tid >> 6;
  int rl  = lane >> 3;                    // 0..7
  int oct = (lane & 7) ^ rl;              // swizzled logical k-octet to fetch

  // A: wave w stages rows w*16 .. w*16+15 (two glls of 8 rows each), gathered.
  int arow0 = row0 + w * 16 + rl, arow1 = arow0 + 8;
  int aidx0 = arow0 < rend ? arow0 : rend - 1;
  int aidx1 = arow1 < rend ? arow1 : rend - 1;
  const unsigned short* agp0 = Xb + (size_t)(rows[aidx0] >> 1) * H_ + oct * 8;
  const unsigned short* agp1 = Xb + (size_t)(rows[aidx1] >> 1) * H_ + oct * 8;

  auto issueA = [&](int buf, int k0) {
    GLOAD_LDS16(agp0 + k0, &As[buf][0] + (w * 16) * 64);
    GLOAD_LDS16(agp1 + k0, &As[buf][0] + (w * 16 + 8) * 64);
  };

  // B: thread covers k-quad kt (4 consecutive k) x 4 consecutive n.
  int kt = tid >> 4;                      // 0..15 (k-quad within BK=64)
  int nt = tid & 15;                      // 0..15 (n-quad within 64 B-cols)
  // Bs row n<32 -> gate col c0+n ; n>=32 -> up col I_+c0+n-32.
  int gbase = (nt < 8) ? (c0 + nt * 4) : (I_ + c0 + (nt - 8) * 4);
  const float* gupe = GUP + (size_t)e * H_ * GU_ + gbase;

  float4 vb[4];
  auto loadB = [&](int k0) {
#pragma unroll
    for (int i = 0; i < 4; ++i)
      vb[i] = *(const float4*)(gupe + (size_t)(k0 + kt * 4 + i) * GU_);
  };
  auto writeB = [&](int buf) {
#pragma unroll
    for (int j = 0; j < 4; ++j) {
      int n = nt * 4 + j;
      unsigned u0 = pk2bf(((const float*)&vb[0])[j], ((const float*)&vb[1])[j]);
      unsigned u1 = pk2bf(((const float*)&vb[2])[j], ((const float*)&vb[3])[j]);
      quad_st(&Bs[buf][0], n, kt, u0, u1);
    }
  };

  int mh = w >> 1, nh = w & 1;
  int m = lane & 15, qf = lane >> 4;
  f32x4 acc[2][2] = {};

  issueA(0, 0);
  loadB(0);
  writeB(0);
  int cur = 0;
  const int niter = H_ / 64;
#pragma unroll 1
  for (int it = 0; it < niter; ++it) {
    __syncthreads();                       // buf[cur] ready (glls + ds_writes)
    if (it + 1 < niter) { issueA(cur ^ 1, (it + 1) * 64); loadB((it + 1) * 64); }
    const unsigned short* a_ = &As[cur][0];
    const unsigned short* b_ = &Bs[cur][0];
#pragma unroll
    for (int kk = 0; kk < 2; ++kk) {
      bf16x8 af0 = frag_ld(a_, mh * 32 + m,      kk * 4 + qf);
      bf16x8 af1 = frag_ld(a_, mh * 32 + 16 + m, kk * 4 + qf);
      bf16x8 bg  = frag_ld(b_, nh * 16 + m,      kk * 4 + qf);
      bf16x8 bu  = frag_ld(b_, 32 + nh * 16 + m, kk * 4 + qf);
      acc[0][0] = MFMA_BF16_16x16x32(af0, bg, acc[0][0], 0, 0, 0);
      acc[0][1] = MFMA_BF16_16x16x32(af0, bu, acc[0][1], 0, 0, 0);
      acc[1][0] = MFMA_BF16_16x16x32(af1, bg, acc[1][0], 0, 0, 0);
      acc[1][1] = MFMA_BF16_16x16x32(af1, bu, acc[1][1], 0, 0, 0);
    }
    if (it + 1 < niter) writeB(cur ^ 1);
    cur ^= 1;
  }

  // epilogue: act = silu(gate)*up ; C/D: col=lane&15, row=qf*4+r
#pragma unroll
  for (int mt = 0; mt < 2; ++mt)
#pragma unroll
    for (int r = 0; r < 4; ++r) {
      int prow = row0 + mh * 32 + mt * 16 + qf * 4 + r;
      if (prow < rend) {
        float g = acc[mt][0][r], u = acc[mt][1][r];
        float a = g / (1.0f + __expf(-g)) * u;
        act[(size_t)prow * I_ + c0 + nh * 16 + m] = (unsigned short)f2bf(a);
      }
    }
}

// ----------------------------------------------------------- fc2 (MFMA) -----
// BM=64, BN=64 out cols, BK=64, double-buffer. B: fp32 direct from DWN
// ([k][n]), in-LDS transpose. Grid: x = 32, y = 8*32 slots.
__global__ __launch_bounds__(256) void fc2_mfma(
    const unsigned short* __restrict__ act, const float* __restrict__ DWN,
    const int* __restrict__ offs, float* __restrict__ fc2buf) {
  __shared__ __align__(16) unsigned short As[2][64 * 64];
  __shared__ __align__(16) unsigned short Bs[2][64 * 64];

  int e    = blockIdx.y >> 5;
  int rbeg = offs[e], rend = offs[e + 1];
  int row0 = rbeg + (blockIdx.y & 31) * 64;
  if (row0 >= rend) return;
  int c0 = blockIdx.x * 64;

  int tid = threadIdx.x, lane = tid & 63, w = tid >> 6;
  int rl  = lane >> 3;
  int oct = (lane & 7) ^ rl;

  int arow0 = row0 + w * 16 + rl, arow1 = arow0 + 8;
  int aidx0 = arow0 < rend ? arow0 : rend - 1;
  int aidx1 = arow1 < rend ? arow1 : rend - 1;
  const unsigned short* agp0 = act + (size_t)aidx0 * I_ + oct * 8;
  const unsigned short* agp1 = act + (size_t)aidx1 * I_ + oct * 8;

  auto issueA = [&](int buf, int k0) {
    GLOAD_LDS16(agp0 + k0, &As[buf][0] + (w * 16) * 64);
    GLOAD_LDS16(agp1 + k0, &As[buf][0] + (w * 16 + 8) * 64);
  };

  int kt = tid >> 4, nt = tid & 15;
  const float* dwe = DWN + (size_t)e * I_ * H_ + c0 + nt * 4;

  float4 vb[4];
  auto loadB = [&](int k0) {
#pragma unroll
    for (int i = 0; i < 4; ++i)
      vb[i] = *(const float4*)(dwe + (size_t)(k0 + kt * 4 + i) * H_);
  };
  auto writeB = [&](int buf) {
#pragma unroll
    for (int j = 0; j < 4; ++j) {
      int n = nt * 4 + j;
      unsigned u0 = pk2bf(((const float*)&vb[0])[j], ((const float*)&vb[1])[j]);
      unsigned u1 = pk2bf(((const float*)&vb[2])[j], ((const float*)&vb[3])[j]);
      quad_st(&Bs[buf][0], n, kt, u0, u1);
    }
  };

  int mh = w >> 1, nh = w & 1;
  int m = lane & 15, qf = lane >> 4;
  f32x4 acc[2][2] = {};

  issueA(0, 0);
  loadB(0);
  writeB(0);
  int cur = 0;
  const int niter = I_ / 64;
#pragma unroll 1
  for (int it = 0; it < niter; ++it) {
    __syncthreads();
    if (it + 1 < niter) { issueA(cur ^ 1, (it + 1) * 64); loadB((it + 1) * 64); }
    const unsigned short* a_ = &As[cur][0];
    const unsigned short* b_ = &Bs[cur][0];
#pragma unroll
    for (int kk = 0; kk < 2; ++kk) {
      bf16x8 af0 = frag_ld(a_, mh * 32 + m,      kk * 4 + qf);
      bf16x8 af1 = frag_ld(a_, mh * 32 + 16 + m, kk * 4 + qf);
      bf16x8 bf0 = frag_ld(b_, nh * 32 + m,      kk * 4 + qf);
      bf16x8 bf1 = frag_ld(b_, nh * 32 + 16 + m, kk * 4 + qf);
      acc[0][0] = MFMA_BF16_16x16x32(af0, bf0, acc[0][0], 0, 0, 0);
      acc[0][1] = MFMA_BF16_16x16x32(af0, bf1, acc[0][1], 0, 0, 0);
      acc[1][0] = MFMA_BF16_16x16x32(af1, bf0, acc[1][0], 0, 0, 0);
      acc[1][1] = MFMA_BF16_16x16x32(af1, bf1, acc[1][1], 0, 0, 0);
    }
    if (it + 1 < niter) writeB(cur ^ 1);
    cur ^= 1;
  }

#pragma unroll
  for (int mt = 0; mt < 2; ++mt)
#pragma unroll
    for (int ntc = 0; ntc < 2; ++ntc)
#pragma unroll
      for (int r = 0; r < 4; ++r) {
        int prow = row0 + mh * 32 + mt * 16 + qf * 4 + r;
        if (prow < rend)
          fc2buf[(size_t)prow * H_ + c0 + nh * 32 + ntc * 16 + m] = acc[mt][ntc][r];
      }
}

// ------------------------------------------------------------- combine -----
__global__ __launch_bounds__(256) void combine_kernel(
    const float* __restrict__ fc2buf, const float* __restrict__ RW,
    const int* __restrict__ inv, float* __restrict__ out) {
  int idx = blockIdx.x * 256 + threadIdx.x;   // T*512 threads, float4 each
  int t = idx >> 9, c4 = idx & 511;
  if (t >= T_) return;
  int r0 = inv[t * 2], r1 = inv[t * 2 + 1];
  float w0 = RW[t * 2], w1 = RW[t * 2 + 1];
  float4 v0 = ((const float4*)(fc2buf + (size_t)r0 * H_))[c4];
  float4 v1 = ((const float4*)(fc2buf + (size_t)r1 * H_))[c4];
  float4 o;
  o.x = w0 * v0.x + w1 * v1.x;
  o.y = w0 * v0.y + w1 * v1.y;
  o.z = w0 * v0.z + w1 * v1.z;
  o.w = w0 * v0.w + w1 * v1.w;
  ((float4*)(out + (size_t)t * H_))[c4] = o;
}

// ------------------------------------------------------------- launcher ----
extern "C" void kernel_launch(void* const* d_in, const int* in_sizes, int n_in,
                              void* d_out, int out_size, void* d_ws, size_t ws_size,
                              hipStream_t stream) {
  const float* X   = (const float*)d_in[0];
  const float* RW  = (const float*)d_in[1];
  const float* GUP = (const float*)d_in[2];
  const float* DWN = (const float*)d_in[3];
  const int*   SEL = (const int*)d_in[4];
  float* out = (float*)d_out;

  char* ws = (char*)d_ws;
  int* offs = (int*)ws;                                   // 64 B
  int* rows = (int*)(ws + 1024);                          // 8 KB
  int* inv  = (int*)(ws + 16384);                         // 8 KB
  unsigned short* Xb  = (unsigned short*)(ws + 32768);    // 4 MB bf16
  unsigned short* act = (unsigned short*)(ws + 32768 + 4194304);        // 3 MB
  float* fc2buf = (float*)(ws + 32768 + 4194304 + 3145728);             // 16 MB

  hipLaunchKernelGGL(prep_kernel, dim3(2049), dim3(256), 0, stream,
                     X, Xb, SEL, offs, rows, inv);
  hipLaunchKernelGGL(fc1_mfma, dim3(24, 256), dim3(256), 0, stream,
                     Xb, GUP, offs, rows, act);
  hipLaunchKernelGGL(fc2_mfma, dim3(32, 256), dim3(256), 0, stream,
                     act, DWN, offs, fc2buf);
  hipLaunchKernelGGL(combine_kernel, dim3(T_ * 2), dim3(256), 0, stream,
                     fc2buf, RW, inv, out);
}

// Round 5
// 252.214 us; speedup vs baseline: 1.2703x; 1.0212x over previous
//
#include <hip/hip_runtime.h>
#include <math.h>

#define E_  8
#define H_  2048
#define I_  768
#define T_  1024
#define K_  2
#define TK_ 2048
#define GU_ 1536   // 2*I

typedef short  short8 __attribute__((ext_vector_type(8)));
typedef __bf16 bf16x8 __attribute__((ext_vector_type(8)));
typedef float  f32x4  __attribute__((ext_vector_type(4)));

static __device__ __forceinline__ short f2bf(float f) {
  union { float f; unsigned u; } v; v.f = f;
  unsigned r = (v.u + 0x7fffu + ((v.u >> 16) & 1u)) >> 16;
  return (short)r;
}

// pack two floats -> two bf16 in one u32 (round-half-up + v_perm)
static __device__ __forceinline__ unsigned pk2bf(float a, float b) {
  unsigned ua = __float_as_uint(a) + 0x8000u;
  unsigned ub = __float_as_uint(b) + 0x8000u;
  return __builtin_amdgcn_perm(ub, ua, 0x07060302u);  // lo=hi16(ua), hi=hi16(ub)
}

#define GLOAD_LDS16(g, l)                                                   \
  __builtin_amdgcn_global_load_lds(                                         \
      (const __attribute__((address_space(1))) void*)(g),                   \
      (__attribute__((address_space(3))) void*)(l), 16, 0, 0)

#define MFMA_BF16_16x16x32 __builtin_amdgcn_mfma_f32_16x16x32_bf16

// A fragment read: row-major [row][64], phys octet = oct ^ (row&7) (2-way=free)
static __device__ __forceinline__ bf16x8 frag_ld(const unsigned short* base,
                                                 int row, int oct) {
  return *(const bf16x8*)(base + row * 64 + ((oct ^ (row & 7)) * 8));
}

// B fragment read: pitch-68 rows (odd 8B multiple -> conflict-free), no swizzle.
// Two 8B-aligned loads (can't merge to misaligned b128).
static __device__ __forceinline__ bf16x8 bfrag_ld(const unsigned short* base,
                                                  int n, int o) {
  const unsigned short* p = base + n * 68 + o * 8;
  uint2 lo = *(const uint2*)p;
  uint2 hi = *(const uint2*)(p + 4);
  union { uint4 u; bf16x8 v; } c;
  c.u = make_uint4(lo.x, lo.y, hi.x, hi.y);
  return c.v;
}

// --------------------------- prep: X cast + out zero + routing --------------
__global__ __launch_bounds__(256) void prep_kernel(
    const float* __restrict__ X, unsigned short* __restrict__ Xb,
    float* __restrict__ out,
    const int* __restrict__ sel, int* __restrict__ offs,
    int* __restrict__ rows) {
  __shared__ int cnt[E_], cur[E_], loff[E_ + 1];
  if (blockIdx.x < 2048) {
    int i = blockIdx.x * 256 + threadIdx.x;     // one float4 each (T*H/4 total)
    float4 v = ((const float4*)X)[i];
    unsigned p0 = pk2bf(v.x, v.y), p1 = pk2bf(v.z, v.w);
    ((uint2*)Xb)[i] = make_uint2(p0, p1);
    ((float4*)out)[i] = make_float4(0.f, 0.f, 0.f, 0.f);  // out: same elem count
    return;
  }
  int t = threadIdx.x;
  if (t < E_) { cnt[t] = 0; cur[t] = 0; }
  __syncthreads();
  for (int p = t; p < TK_; p += 256) atomicAdd(&cnt[sel[p]], 1);
  __syncthreads();
  if (t == 0) {
    int s = 0;
    for (int e = 0; e < E_; ++e) { loff[e] = s; s += cnt[e]; }
    loff[E_] = s;
  }
  __syncthreads();
  if (t <= E_) offs[t] = loff[t];
  for (int p = t; p < TK_; p += 256) {
    int e = sel[p];
    int pos = loff[e] + atomicAdd(&cur[e], 1);
    rows[pos] = p;
  }
}

// --------------------------------------------------- fc1 (MFMA) + swiglu ----
// BM=128 rows, 32 act cols (32 gate + 32 up B-rows), BK=64, double-buffer.
// A: bf16 gathered via global_load_lds. B: fp32 [k][n] direct, in-LDS
// transpose+cast, pitch-68 conflict-free layout.
// Grid: x = 24 (act-col tiles of 32), y = 8 experts * 16 slots of 128 rows.
__global__ __launch_bounds__(256) void fc1_mfma(
    const unsigned short* __restrict__ Xb, const float* __restrict__ GUP,
    const int* __restrict__ offs, const int* __restrict__ rows,
    unsigned short* __restrict__ act) {
  __shared__ __align__(16) unsigned short As[2][128 * 64];  // 32 KB
  __shared__ __align__(16) unsigned short Bs[2][64 * 68];   // 17 KB

  int e    = blockIdx.y >> 4;
  int rbeg = offs[e], rend = offs[e + 1];
  int row0 = rbeg + (blockIdx.y & 15) * 128;
  if (row0 >= rend) return;
  int c0 = blockIdx.x * 32;

  int tid = threadIdx.x, lane = tid & 63, w = tid >> 6;
  int rl  = lane >> 3;                    // 0..7
  int oct = (lane & 7) ^ rl;              // A-side global octet swizzle

  // A: wave w owns rows w*32 .. w*32+31, staged as 4 glls of 8 rows.
  const unsigned short* agp[4];
#pragma unroll
  for (int i = 0; i < 4; ++i) {
    int arow = row0 + w * 32 + i * 8 + rl;
    int aidx = arow < rend ? arow : rend - 1;
    agp[i] = Xb + (size_t)(rows[aidx] >> 1) * H_ + oct * 8;
  }
  auto issueA = [&](int buf, int k0) {
#pragma unroll
    for (int i = 0; i < 4; ++i)
      GLOAD_LDS16(agp[i] + k0, &As[buf][0] + (w * 32 + i * 8) * 64);
  };

  // B: thread covers k-quad kt x 4 consecutive n; n<32 gate, n>=32 up.
  int kt = tid >> 4, nt = tid & 15;
  int gbase = (nt < 8) ? (c0 + nt * 4) : (I_ + c0 + (nt - 8) * 4);
  const float* gupe = GUP + (size_t)e * H_ * GU_ + gbase;

  float4 vb[4];
  auto loadB = [&](int k0) {
#pragma unroll
    for (int i = 0; i < 4; ++i)
      vb[i] = *(const float4*)(gupe + (size_t)(k0 + kt * 4 + i) * GU_);
  };
  auto writeB = [&](int buf) {
#pragma unroll
    for (int j = 0; j < 4; ++j) {
      int n = nt * 4 + j;
      unsigned u0 = pk2bf(((const float*)&vb[0])[j], ((const float*)&vb[1])[j]);
      unsigned u1 = pk2bf(((const float*)&vb[2])[j], ((const float*)&vb[3])[j]);
      *(uint2*)(&Bs[buf][0] + n * 68 + kt * 4) = make_uint2(u0, u1);
    }
  };

  int m = lane & 15, qf = lane >> 4;
  f32x4 acc[2][4] = {};

  issueA(0, 0);
  loadB(0);
  writeB(0);
  int cur = 0;
  const int niter = H_ / 64;
#pragma unroll 1
  for (int it = 0; it < niter; ++it) {
    __syncthreads();                      // buf[cur] ready
    if (it + 1 < niter) { issueA(cur ^ 1, (it + 1) * 64); loadB((it + 1) * 64); }
    const unsigned short* a_ = &As[cur][0];
    const unsigned short* b_ = &Bs[cur][0];
#pragma unroll
    for (int kk = 0; kk < 2; ++kk) {
      int o = kk * 4 + qf;
      bf16x8 af0 = frag_ld(a_, w * 32 + m,      o);
      bf16x8 af1 = frag_ld(a_, w * 32 + 16 + m, o);
      bf16x8 b0  = bfrag_ld(b_, m,      o);
      bf16x8 b1  = bfrag_ld(b_, 16 + m, o);
      bf16x8 b2  = bfrag_ld(b_, 32 + m, o);
      bf16x8 b3  = bfrag_ld(b_, 48 + m, o);
      acc[0][0] = MFMA_BF16_16x16x32(af0, b0, acc[0][0], 0, 0, 0);
      acc[0][1] = MFMA_BF16_16x16x32(af0, b1, acc[0][1], 0, 0, 0);
      acc[0][2] = MFMA_BF16_16x16x32(af0, b2, acc[0][2], 0, 0, 0);
      acc[0][3] = MFMA_BF16_16x16x32(af0, b3, acc[0][3], 0, 0, 0);
      acc[1][0] = MFMA_BF16_16x16x32(af1, b0, acc[1][0], 0, 0, 0);
      acc[1][1] = MFMA_BF16_16x16x32(af1, b1, acc[1][1], 0, 0, 0);
      acc[1][2] = MFMA_BF16_16x16x32(af1, b2, acc[1][2], 0, 0, 0);
      acc[1][3] = MFMA_BF16_16x16x32(af1, b3, acc[1][3], 0, 0, 0);
    }
    if (it + 1 < niter) writeB(cur ^ 1);
    cur ^= 1;
  }

  // epilogue: act = silu(gate)*up ; gate tiles 0,1 pair with up tiles 2,3.
#pragma unroll
  for (int mt = 0; mt < 2; ++mt)
#pragma unroll
    for (int g = 0; g < 2; ++g)
#pragma unroll
      for (int r = 0; r < 4; ++r) {
        int prow = row0 + w * 32 + mt * 16 + qf * 4 + r;
        if (prow < rend) {
          float gv = acc[mt][g][r], uv = acc[mt][g + 2][r];
          float a = gv / (1.0f + __expf(-gv)) * uv;
          act[(size_t)prow * I_ + c0 + g * 16 + m] = (unsigned short)f2bf(a);
        }
      }
}

// ------------------------------------- fc2 (MFMA) + fused weighted combine --
// BM=128, BN=64 out cols, BK=64, double-buffer; epilogue atomics into out.
// Grid: x = 32, y = 8 experts * 16 slots of 128 rows.
__global__ __launch_bounds__(256) void fc2_mfma(
    const unsigned short* __restrict__ act, const float* __restrict__ DWN,
    const float* __restrict__ RW,
    const int* __restrict__ offs, const int* __restrict__ rows,
    float* __restrict__ out) {
  __shared__ __align__(16) unsigned short As[2][128 * 64];
  __shared__ __align__(16) unsigned short Bs[2][64 * 68];

  int e    = blockIdx.y >> 4;
  int rbeg = offs[e], rend = offs[e + 1];
  int row0 = rbeg + (blockIdx.y & 15) * 128;
  if (row0 >= rend) return;
  int c0 = blockIdx.x * 64;

  int tid = threadIdx.x, lane = tid & 63, w = tid >> 6;
  int rl  = lane >> 3;
  int oct = (lane & 7) ^ rl;

  const unsigned short* agp[4];
#pragma unroll
  for (int i = 0; i < 4; ++i) {
    int arow = row0 + w * 32 + i * 8 + rl;
    int aidx = arow < rend ? arow : rend - 1;
    agp[i] = act + (size_t)aidx * I_ + oct * 8;
  }
  auto issueA = [&](int buf, int k0) {
#pragma unroll
    for (int i = 0; i < 4; ++i)
      GLOAD_LDS16(agp[i] + k0, &As[buf][0] + (w * 32 + i * 8) * 64);
  };

  int kt = tid >> 4, nt = tid & 15;
  const float* dwe = DWN + (size_t)e * I_ * H_ + c0 + nt * 4;

  float4 vb[4];
  auto loadB = [&](int k0) {
#pragma unroll
    for (int i = 0; i < 4; ++i)
      vb[i] = *(const float4*)(dwe + (size_t)(k0 + kt * 4 + i) * H_);
  };
  auto writeB = [&](int buf) {
#pragma unroll
    for (int j = 0; j < 4; ++j) {
      int n = nt * 4 + j;
      unsigned u0 = pk2bf(((const float*)&vb[0])[j], ((const float*)&vb[1])[j]);
      unsigned u1 = pk2bf(((const float*)&vb[2])[j], ((const float*)&vb[3])[j]);
      *(uint2*)(&Bs[buf][0] + n * 68 + kt * 4) = make_uint2(u0, u1);
    }
  };

  int m = lane & 15, qf = lane >> 4;
  f32x4 acc[2][4] = {};

  issueA(0, 0);
  loadB(0);
  writeB(0);
  int cur = 0;
  const int niter = I_ / 64;
#pragma unroll 1
  for (int it = 0; it < niter; ++it) {
    __syncthreads();
    if (it + 1 < niter) { issueA(cur ^ 1, (it + 1) * 64); loadB((it + 1) * 64); }
    const unsigned short* a_ = &As[cur][0];
    const unsigned short* b_ = &Bs[cur][0];
#pragma unroll
    for (int kk = 0; kk < 2; ++kk) {
      int o = kk * 4 + qf;
      bf16x8 af0 = frag_ld(a_, w * 32 + m,      o);
      bf16x8 af1 = frag_ld(a_, w * 32 + 16 + m, o);
      bf16x8 b0  = bfrag_ld(b_, m,      o);
      bf16x8 b1  = bfrag_ld(b_, 16 + m, o);
      bf16x8 b2  = bfrag_ld(b_, 32 + m, o);
      bf16x8 b3  = bfrag_ld(b_, 48 + m, o);
      acc[0][0] = MFMA_BF16_16x16x32(af0, b0, acc[0][0], 0, 0, 0);
      acc[0][1] = MFMA_BF16_16x16x32(af0, b1, acc[0][1], 0, 0, 0);
      acc[0][2] = MFMA_BF16_16x16x32(af0, b2, acc[0][2], 0, 0, 0);
      acc[0][3] = MFMA_BF16_16x16x32(af0, b3, acc[0][3], 0, 0, 0);
      acc[1][0] = MFMA_BF16_16x16x32(af1, b0, acc[1][0], 0, 0, 0);
      acc[1][1] = MFMA_BF16_16x16x32(af1, b1, acc[1][1], 0, 0, 0);
      acc[1][2] = MFMA_BF16_16x16x32(af1, b2, acc[1][2], 0, 0, 0);
      acc[1][3] = MFMA_BF16_16x16x32(af1, b3, acc[1][3], 0, 0, 0);
    }
    if (it + 1 < niter) writeB(cur ^ 1);
    cur ^= 1;
  }

  // epilogue: out[token] += rw * fc2  (out zeroed by prep)
#pragma unroll
  for (int mt = 0; mt < 2; ++mt)
#pragma unroll
    for (int r = 0; r < 4; ++r) {
      int prow = row0 + w * 32 + mt * 16 + qf * 4 + r;
      if (prow < rend) {
        int pair = rows[prow];
        float rw = RW[pair];
        float* orow = out + (size_t)(pair >> 1) * H_ + c0 + m;
#pragma unroll
        for (int ntile = 0; ntile < 4; ++ntile)
          atomicAdd(orow + ntile * 16, rw * acc[mt][ntile][r]);
      }
    }
}

// ------------------------------------------------------------- launcher ----
extern "C" void kernel_launch(void* const* d_in, const int* in_sizes, int n_in,
                              void* d_out, int out_size, void* d_ws, size_t ws_size,
                              hipStream_t stream) {
  const float* X   = (const float*)d_in[0];
  const float* RW  = (const float*)d_in[1];
  const float* GUP = (const float*)d_in[2];
  const float* DWN = (const float*)d_in[3];
  const int*   SEL = (const int*)d_in[4];
  float* out = (float*)d_out;

  char* ws = (char*)d_ws;
  int* offs = (int*)ws;                                   // 64 B
  int* rows = (int*)(ws + 1024);                          // 8 KB
  unsigned short* Xb  = (unsigned short*)(ws + 16384);    // 4 MB bf16
  unsigned short* act = (unsigned short*)(ws + 16384 + 4194304);  // 3 MB bf16

  hipLaunchKernelGGL(prep_kernel, dim3(2049), dim3(256), 0, stream,
                     X, Xb, out, SEL, offs, rows);
  hipLaunchKernelGGL(fc1_mfma, dim3(24, 128), dim3(256), 0, stream,
                     Xb, GUP, offs, rows, act);
  hipLaunchKernelGGL(fc2_mfma, dim3(32, 128), dim3(256), 0, stream,
                     act, DWN, RW, offs, rows, out);
}